// Round 16
// baseline (324.727 us; speedup 1.0000x reference)
//
#include <hip/hip_runtime.h>
#include <hip/hip_bf16.h>
#include <math.h>

// ---------------------------------------------------------------------------
// ROUND 16 = ATTRIBUTION EXPERIMENT. Functionally identical to round 15, but
// conv_scan repeats its body CREPS times (reps>0 -> dummy feats rows) and
// mlp_kernel repeats its tile body MREPS times (idempotent). This forces both
// kernels above the harness's ~40us poison fills into rocprof's top-5 WITH
// counters, and per-dispatch dur gives unit costs (conv/10, mlp/6).
// ---------------------------------------------------------------------------

typedef __attribute__((ext_vector_type(8))) short short8;
typedef __attribute__((ext_vector_type(4))) float f32x4;

#define WT_N 81920    // 10*32*32*8
#define RCAP 30720    // per-depth run-list capacity
#define RSTRIDE 32    // gcnt padding (ints): one counter per 128B line
#define FSLOTS 256    // real feats_part rows
#define FROWS  512    // incl. dummy rows [256,512) for rep>0 writes
#define CREPS 10
#define MREPS 6

__device__ __forceinline__ unsigned short f2bf(float x) {
    __hip_bfloat16 h = __float2bfloat16(x);
    return *reinterpret_cast<unsigned short*>(&h);
}
__device__ __forceinline__ float bf2f(unsigned short h) {
    union { float f; unsigned u; } v; v.u = ((unsigned)h) << 16;
    return v.f;
}

__device__ __forceinline__ float4 shfl4(float4 v, int src) {
    float4 r;
    r.x = __shfl(v.x, src, 64);
    r.y = __shfl(v.y, src, 64);
    r.z = __shfl(v.z, src, 64);
    r.w = __shfl(v.w, src, 64);
    return r;
}

__device__ __forceinline__ void red_ig(float4& T) {
    #pragma unroll
    for (int m = 8; m <= 32; m <<= 1) {
        T.x += __shfl_xor(T.x, m, 64);
        T.y += __shfl_xor(T.y, m, 64);
        T.z += __shfl_xor(T.z, m, 64);
        T.w += __shfl_xor(T.w, m, 64);
    }
}

__device__ __forceinline__ float gelu_fast(float x)
{
    float e = __expf(-1.702f * x);
    return x * __builtin_amdgcn_rcpf(1.0f + e);
}

// Kernel Z: zero gcnt.
__global__ __launch_bounds__(256) void zero_kernel(int* __restrict__ dst)
{
    int i = blockIdx.x * 256 + threadIdx.x;
    if (i < 10 * RSTRIDE) dst[i] = 0;
}

// Kernel 0: W transpose / run detect / w1 pack / feats_part zero (FROWS rows).
__global__ __launch_bounds__(256) void prep_kernel(
    const float* __restrict__ conv_w, float* __restrict__ Wt,
    const float* __restrict__ hf_w1, const float* __restrict__ hs_w1,
    short* __restrict__ bph, short* __restrict__ bpl,
    const int* __restrict__ idx_sorted, const int* __restrict__ node_depth,
    int* __restrict__ gcnt, int2* __restrict__ runlist,
    float* __restrict__ feats_part, int M)
{
    __shared__ float tl[32 * 257];
    __shared__ int hcnt[16], hbase[16];

    if (blockIdx.x < 10) {
        int d = blockIdx.x;
        int base = d * 8192;
        for (int t = threadIdx.x; t < 8192; t += 256)
            tl[(t >> 8) * 257 + (t & 255)] = conv_w[base + t];
        __syncthreads();
        for (int t = threadIdx.x; t < 8192; t += 256) {
            int o = t & 31, i = (t >> 5) & 31, k = t >> 10;
            Wt[base + t] = tl[o * 257 + i * 8 + k];
        }
        return;
    }

    if (threadIdx.x < 16) hcnt[threadIdx.x] = 0;
    __syncthreads();

    int j = (blockIdx.x - 10) * 256 + threadIdx.x;
    bool start = false;
    int d = 0, myp = 0, mypos = 0;

    if (j < M) {
        int p = idx_sorted[j] >> 3;
        start = (j == 0) || ((idx_sorted[j - 1] >> 3) != p);
        if (start) {
            d = node_depth[p];
            myp = p;
            mypos = atomicAdd(&hcnt[d], 1);
        }
    } else if (j < M + 512) {
        int jj = j - M;
        int lane = jj & 63;
        int q = jj >> 6;
        int m = q >> 2, tq = q & 3;
        int kg = lane >> 4, n0 = lane & 15, k0 = kg * 8;
        const float* __restrict__ w1 = m ? hs_w1 : hf_w1;
        #pragma unroll
        for (int i = 0; i < 8; ++i) {
            float w = w1[(k0 + i) * 64 + tq * 16 + n0];
            unsigned short hh = f2bf(w);
            bph[(q * 64 + lane) * 8 + i] = (short)hh;
            bpl[(q * 64 + lane) * 8 + i] = (short)f2bf(w - bf2f(hh));
        }
    } else if (j < M + 512 + FROWS * 32) {
        feats_part[j - (M + 512)] = 0.0f;
    }

    __syncthreads();
    if (threadIdx.x < 16) {
        int c = hcnt[threadIdx.x];
        if (c > 0) hbase[threadIdx.x] = atomicAdd(&gcnt[threadIdx.x * RSTRIDE], c);
    }
    __syncthreads();
    if (start) runlist[d * RCAP + hbase[d] + mypos] = make_int2(j, myp);
}

// Per-run sequential steps (inline).
__device__ __forceinline__ void run_steps(
    float4& T, float4& blk, float4& pfs, int ec, float edw, int base16,
    int n, int p, bool valid, const float* __restrict__ W, float4 bias,
    int og, int og8, int ig, float* __restrict__ patch)
{
    if (!valid) return;
    int c = __shfl(ec, base16, 64);
    float4 wc0 = *(const float4*)(W + (c * 32 + ig * 4 + 0) * 32 + og);
    float4 wc1 = *(const float4*)(W + (c * 32 + ig * 4 + 1) * 32 + og);
    float4 wc2 = *(const float4*)(W + (c * 32 + ig * 4 + 2) * 32 + og);
    float4 wc3 = *(const float4*)(W + (c * 32 + ig * 4 + 3) * 32 + og);

    for (int s = 0;; ++s) {
        float dw = __shfl(edw, base16 + s, 64);
        float4 feat = {T.x + bias.x, T.y + bias.y, T.z + bias.z, T.w + bias.w};
        pfs.x = fmaf(dw, feat.x, pfs.x); pfs.y = fmaf(dw, feat.y, pfs.y);
        pfs.z = fmaf(dw, feat.z, pfs.z); pfs.w = fmaf(dw, feat.w, pfs.w);

        if (s + 1 == n) {
            if (p == 0 && c == 0 && ig == 0)
                *(float4*)(patch + og) = feat;
            return;
        }

        int cn = __shfl(ec, base16 + s + 1, 64);
        float4 nw0 = *(const float4*)(W + (cn * 32 + ig * 4 + 0) * 32 + og);
        float4 nw1 = *(const float4*)(W + (cn * 32 + ig * 4 + 1) * 32 + og);
        float4 nw2 = *(const float4*)(W + (cn * 32 + ig * 4 + 2) * 32 + og);
        float4 nw3 = *(const float4*)(W + (cn * 32 + ig * 4 + 3) * 32 + og);

        float4 ov = shfl4(blk, c * 8 + og8);
        float4 du = {feat.x - ov.x, feat.y - ov.y, feat.z - ov.z, feat.w - ov.w};
        if (ig == c) blk = feat;
        float4 u = shfl4(du, og8 * 8 + ig);

        float4 a4;
        a4.x = u.x * wc0.x; a4.y = u.x * wc0.y;
        a4.z = u.x * wc0.z; a4.w = u.x * wc0.w;
        a4.x = fmaf(u.y, wc1.x, a4.x); a4.y = fmaf(u.y, wc1.y, a4.y);
        a4.z = fmaf(u.y, wc1.z, a4.z); a4.w = fmaf(u.y, wc1.w, a4.w);
        a4.x = fmaf(u.z, wc2.x, a4.x); a4.y = fmaf(u.z, wc2.y, a4.y);
        a4.z = fmaf(u.z, wc2.z, a4.z); a4.w = fmaf(u.z, wc2.w, a4.w);
        a4.x = fmaf(u.w, wc3.x, a4.x); a4.y = fmaf(u.w, wc3.y, a4.y);
        a4.z = fmaf(u.w, wc3.z, a4.z); a4.w = fmaf(u.w, wc3.w, a4.w);
        red_ig(a4);
        T.x += a4.x; T.y += a4.y; T.z += a4.z; T.w += a4.w;

        c = cn;
        wc0 = nw0; wc1 = nw1; wc2 = nw2; wc3 = nw3;
    }
}

#define FMA16(T, X) \
    T.x = fmaf(X.x, w0.x, T.x); T.y = fmaf(X.x, w0.y, T.y); \
    T.z = fmaf(X.x, w0.z, T.z); T.w = fmaf(X.x, w0.w, T.w); \
    T.x = fmaf(X.y, w1.x, T.x); T.y = fmaf(X.y, w1.y, T.y); \
    T.z = fmaf(X.y, w1.z, T.z); T.w = fmaf(X.y, w1.w, T.w); \
    T.x = fmaf(X.z, w2.x, T.x); T.y = fmaf(X.z, w2.y, T.y); \
    T.z = fmaf(X.z, w2.z, T.z); T.w = fmaf(X.z, w2.w, T.w); \
    T.x = fmaf(X.w, w3.x, T.x); T.y = fmaf(X.w, w3.y, T.y); \
    T.z = fmaf(X.w, w3.z, T.z); T.w = fmaf(X.w, w3.w, T.w);

// Kernel 1: conv; body repeated CREPS times (rep>0 -> dummy feats rows).
__global__ __launch_bounds__(256, 4) void conv_scan(
    const float* __restrict__ data, const float* __restrict__ Wt,
    const float* __restrict__ conv_b, const float* __restrict__ depth_weight,
    const int* __restrict__ idx_sorted, const int* __restrict__ depth_sorted,
    const int* __restrict__ gcnt, const int2* __restrict__ runlist,
    float* __restrict__ feats_part, float* __restrict__ patch, int M)
{
    __shared__ float fred[4][32];

    int w = (blockIdx.x * 256 + threadIdx.x) >> 6;
    int l = threadIdx.x & 63;
    int wv = threadIdx.x >> 6;
    int og8 = l & 7, og = og8 * 4, ig = l >> 3;
    int q = l >> 4;

    int acc = 0, d = -1, chunk = 0, cnt = 0;
    #pragma unroll
    for (int dd = 0; dd < 10; ++dd) {
        int c = gcnt[dd * RSTRIDE];
        int nw = (c + 3) >> 2;
        if (d < 0 && w < acc + nw) { d = dd; chunk = w - acc; cnt = c; }
        acc += nw;
    }

    #pragma unroll 1
    for (int rep = 0; rep < CREPS; ++rep) {
        int zoff = 0;
        asm volatile("" : "+v"(zoff));   // defeat LICM across reps

        float4 pfs = {0, 0, 0, 0};
        if (d >= 0) {
            int r0 = chunk * 4;
            int rq = r0 + q; if (rq >= cnt) rq = cnt - 1;
            int2 e = runlist[d * RCAP + rq + zoff];
            int t0l = e.x, pl = e.y;

            int wl = l & 15;
            int tw = t0l + wl;
            int twc = tw < M ? tw : M - 1;
            int iw  = idx_sorted[twc + zoff];
            int dsw = depth_sorted[twc];
            unsigned long long mask = __ballot((tw < M) && ((iw >> 3) == pl));
            int   ec  = iw & 7;
            float edw = depth_weight[dsw & 15];

            const float* __restrict__ W = Wt + d * 8192 + zoff;
            const float4 bias = *(const float4*)(conv_b + d * 32 + og);

            int p0 = __shfl(pl, 0, 64),  p1 = __shfl(pl, 16, 64),
                p2 = __shfl(pl, 32, 64), p3 = __shfl(pl, 48, 64);
            int n0 = __builtin_ctz(~(unsigned)( mask        & 0xFFFFull));
            int n1 = __builtin_ctz(~(unsigned)((mask >> 16) & 0xFFFFull));
            int n2 = __builtin_ctz(~(unsigned)((mask >> 32) & 0xFFFFull));
            int n3 = __builtin_ctz(~(unsigned)((mask >> 48) & 0xFFFFull));
            bool v0 = (r0 + 0 < cnt), v1 = (r0 + 1 < cnt),
                 v2 = (r0 + 2 < cnt), v3 = (r0 + 3 < cnt);

            float4 B0 = *(const float4*)(data + (size_t)p0 * 256 + ig * 32 + og + zoff);
            float4 B1 = *(const float4*)(data + (size_t)p1 * 256 + ig * 32 + og + zoff);
            float4 B2 = *(const float4*)(data + (size_t)p2 * 256 + ig * 32 + og + zoff);
            float4 B3 = *(const float4*)(data + (size_t)p3 * 256 + ig * 32 + og + zoff);

            float4 T0 = {0,0,0,0}, T1 = {0,0,0,0}, T2 = {0,0,0,0}, T3 = {0,0,0,0};
            #pragma unroll
            for (int k = 0; k < 8; ++k) {
                const float4 w0 = *(const float4*)(W + (k * 32 + ig * 4 + 0) * 32 + og);
                const float4 w1 = *(const float4*)(W + (k * 32 + ig * 4 + 1) * 32 + og);
                const float4 w2 = *(const float4*)(W + (k * 32 + ig * 4 + 2) * 32 + og);
                const float4 w3 = *(const float4*)(W + (k * 32 + ig * 4 + 3) * 32 + og);
                int src = k * 8 + ig;
                float4 x0 = shfl4(B0, src), x1 = shfl4(B1, src),
                       x2 = shfl4(B2, src), x3 = shfl4(B3, src);
                FMA16(T0, x0); FMA16(T1, x1); FMA16(T2, x2); FMA16(T3, x3);
            }
            red_ig(T0); red_ig(T1); red_ig(T2); red_ig(T3);

            run_steps(T0, B0, pfs, ec, edw,  0, n0, p0, v0, W, bias, og, og8, ig, patch);
            run_steps(T1, B1, pfs, ec, edw, 16, n1, p1, v1, W, bias, og, og8, ig, patch);
            run_steps(T2, B2, pfs, ec, edw, 32, n2, p2, v2, W, bias, og, og8, ig, patch);
            run_steps(T3, B3, pfs, ec, edw, 48, n3, p3, v3, W, bias, og, og8, ig, patch);
        }

        if (ig == 0) {
            fred[wv][og + 0] = pfs.x;
            fred[wv][og + 1] = pfs.y;
            fred[wv][og + 2] = pfs.z;
            fred[wv][og + 3] = pfs.w;
        }
        __syncthreads();
        if (threadIdx.x < 32) {
            float s = fred[0][threadIdx.x] + fred[1][threadIdx.x]
                    + fred[2][threadIdx.x] + fred[3][threadIdx.x];
            int row = (blockIdx.x & (FSLOTS - 1)) + (rep ? FSLOTS : 0);
            atomicAdd(&feats_part[row * 32 + threadIdx.x], s);
        }
        __syncthreads();
    }
}

// Kernel 2: mlp; tile body repeated MREPS times (idempotent out stores).
__global__ __launch_bounds__(256, 4) void mlp_kernel(
    const float* __restrict__ data, const float* __restrict__ feats_part,
    const float* __restrict__ patch, const int* __restrict__ leaf_idx,
    const short* __restrict__ bph, const short* __restrict__ bpl,
    const float* __restrict__ hf_w1, const float* __restrict__ hs_w1,
    const float* __restrict__ hf_b1, const float* __restrict__ hf_w2,
    const float* __restrict__ hf_b2, const float* __restrict__ hs_b1,
    const float* __restrict__ hs_w2, const float* __restrict__ hs_b2,
    float* __restrict__ out, int L)
{
    __shared__ float red[256];
    __shared__ float sh_fts[32];
    __shared__ float sh_fvec[128];
    __shared__ __align__(16) short sh_b[4096];

    {
        int ch = threadIdx.x & 31, g = threadIdx.x >> 5;
        float s = 0.f;
        #pragma unroll
        for (int j = 0; j < FSLOTS / 8; ++j)
            s += feats_part[(g + j * 8) * 32 + ch];
        red[threadIdx.x] = s;
        __syncthreads();
        if (threadIdx.x < 128) red[threadIdx.x] += red[threadIdx.x + 128];
        __syncthreads();
        if (threadIdx.x < 64) red[threadIdx.x] += red[threadIdx.x + 64];
        __syncthreads();
        if (threadIdx.x < 32)
            sh_fts[threadIdx.x] = red[threadIdx.x] + red[threadIdx.x + 32];
        __syncthreads();
    }

    {
        const int4* src = (const int4*)bph;
        int4* dst = (int4*)sh_b;
        for (int t = threadIdx.x; t < 512; t += 256) dst[t] = src[t];

        if (threadIdx.x < 128) {
            int m = threadIdx.x >> 6, h = threadIdx.x & 63;
            const float* __restrict__ w1 = m ? hs_w1 : hf_w1;
            float s = 0.f;
            #pragma unroll
            for (int k = 0; k < 32; ++k) s = fmaf(sh_fts[k], w1[k * 64 + h], s);
            sh_fvec[threadIdx.x] = s;
        }
        __syncthreads();
    }

    int l = threadIdx.x & 63;
    int ck = blockIdx.x * 4 + (threadIdx.x >> 6);
    int nchunks = (L + 63) >> 6;
    if (ck >= nchunks) return;
    int base = ck * 64;
    int n0 = l & 15, kg = l >> 4, k0 = kg * 8;

    float w2r[16], b1r[8];
    #pragma unroll
    for (int t = 0; t < 4; ++t) {
        int h = t * 16 + n0;
        w2r[t * 4 + 0] = hf_w2[h * 3 + 0];
        w2r[t * 4 + 1] = hf_w2[h * 3 + 1];
        w2r[t * 4 + 2] = hf_w2[h * 3 + 2];
        w2r[t * 4 + 3] = hs_w2[h];
        b1r[t]     = hf_b1[h] + sh_fvec[h];
        b1r[4 + t] = hs_b1[h] + sh_fvec[64 + h];
    }
    float b20 = hf_b2[0], b21 = hf_b2[1], b22 = hf_b2[2], b23 = hs_b2[0];

    #pragma unroll 1
    for (int rep = 0; rep < MREPS; ++rep) {
        int moff = 0;
        asm volatile("" : "+v"(moff));   // defeat LICM across reps

        #pragma unroll
        for (int tm = 0; tm < 4; ++tm) {
            int r  = base + tm * 16 + n0;
            int rc = r < L ? r : L - 1;
            int row = leaf_idx[rc + moff];
            const float* __restrict__ src = (row == 0) ? patch : (data + (size_t)row * 32);
            float4 vA = *(const float4*)(src + k0 + moff);
            float4 vB = *(const float4*)(src + k0 + 4 + moff);
            float xv[8] = {vA.x, vA.y, vA.z, vA.w, vB.x, vB.y, vB.z, vB.w};
            short8 ahi;
            #pragma unroll
            for (int i = 0; i < 8; ++i) ahi[i] = (short)f2bf(xv[i]);

            f32x4 acc[8];
            bool anyPatch = __any(row == 0);
            if (!anyPatch) {
                #pragma unroll
                for (int qq = 0; qq < 8; ++qq) {
                    short8 bh = *(const short8*)(sh_b + (qq * 64 + l) * 8 + moff);
                    float bv = b1r[qq];
                    f32x4 a = (f32x4){bv, bv, bv, bv};
                    acc[qq] = __builtin_amdgcn_mfma_f32_16x16x32_bf16(ahi, bh, a, 0, 0, 0);
                }
            } else {
                short8 alo;
                #pragma unroll
                for (int i = 0; i < 8; ++i) {
                    unsigned short hh = (unsigned short)ahi[i];
                    alo[i] = (short)f2bf(xv[i] - bf2f(hh));
                }
                #pragma unroll
                for (int qq = 0; qq < 8; ++qq) {
                    short8 bh = *(const short8*)(sh_b + (qq * 64 + l) * 8 + moff);
                    short8 bl = *(const short8*)(bpl + (qq * 64 + l) * 8);
                    float bv = b1r[qq];
                    f32x4 a = (f32x4){bv, bv, bv, bv};
                    a = __builtin_amdgcn_mfma_f32_16x16x32_bf16(ahi, bh, a, 0, 0, 0);
                    a = __builtin_amdgcn_mfma_f32_16x16x32_bf16(alo, bh, a, 0, 0, 0);
                    a = __builtin_amdgcn_mfma_f32_16x16x32_bf16(ahi, bl, a, 0, 0, 0);
                    acc[qq] = a;
                }
            }

            float o[4][4];
            #pragma unroll
            for (int g2 = 0; g2 < 4; ++g2) {
                #pragma unroll
                for (int c = 0; c < 4; ++c) o[g2][c] = 0.f;
            }
            #pragma unroll
            for (int t = 0; t < 4; ++t) {
                #pragma unroll
                for (int reg = 0; reg < 4; ++reg) {
                    float gf = gelu_fast(acc[t][reg]);
                    float gs = gelu_fast(acc[4 + t][reg]);
                    o[reg][0] = fmaf(gf, w2r[t * 4 + 0], o[reg][0]);
                    o[reg][1] = fmaf(gf, w2r[t * 4 + 1], o[reg][1]);
                    o[reg][2] = fmaf(gf, w2r[t * 4 + 2], o[reg][2]);
                    o[reg][3] = fmaf(gs, w2r[t * 4 + 3], o[reg][3]);
                }
            }
            #pragma unroll
            for (int mk = 1; mk < 16; mk <<= 1) {
                #pragma unroll
                for (int reg = 0; reg < 4; ++reg) {
                    #pragma unroll
                    for (int c = 0; c < 4; ++c)
                        o[reg][c] += __shfl_xor(o[reg][c], mk, 64);
                }
            }
            if (n0 < 4) {
                int rL = base + tm * 16 + kg * 4 + n0;
                if (rL < L) {
                    float s0 = n0 == 0 ? o[0][0] : n0 == 1 ? o[1][0] : n0 == 2 ? o[2][0] : o[3][0];
                    float s1 = n0 == 0 ? o[0][1] : n0 == 1 ? o[1][1] : n0 == 2 ? o[2][1] : o[3][1];
                    float s2 = n0 == 0 ? o[0][2] : n0 == 1 ? o[1][2] : n0 == 2 ? o[2][2] : o[3][2];
                    float s3 = n0 == 0 ? o[0][3] : n0 == 1 ? o[1][3] : n0 == 2 ? o[2][3] : o[3][3];
                    float4 res = {s0 + b20, s1 + b21, s2 + b22, s3 + b23};
                    *(float4*)(out + (size_t)rL * 4) = res;
                }
            }
        }
    }
}

extern "C" void kernel_launch(void* const* d_in, const int* in_sizes, int n_in,
                              void* d_out, int out_size, void* d_ws, size_t ws_size,
                              hipStream_t stream)
{
    const float* data         = (const float*)d_in[0];
    const float* conv_w       = (const float*)d_in[1];
    const float* conv_b       = (const float*)d_in[2];
    const float* depth_weight = (const float*)d_in[3];
    const float* hf_w1        = (const float*)d_in[4];
    const float* hf_b1        = (const float*)d_in[5];
    const float* hf_w2        = (const float*)d_in[6];
    const float* hf_b2        = (const float*)d_in[7];
    const float* hs_w1        = (const float*)d_in[8];
    const float* hs_b1        = (const float*)d_in[9];
    const float* hs_w2        = (const float*)d_in[10];
    const float* hs_b2        = (const float*)d_in[11];
    const int*   idx_sorted   = (const int*)d_in[12];
    const int*   depth_sorted = (const int*)d_in[13];
    const int*   node_depth   = (const int*)d_in[14];
    const int*   leaf_idx     = (const int*)d_in[15];

    int M = in_sizes[12];   // 30000
    int L = in_sizes[15];   // 210001
    float* out = (float*)d_out;

    float* Wt         = (float*)d_ws;
    float* patch      = Wt + WT_N;
    short* bph        = (short*)(patch + 32);
    short* bpl        = bph + 4096;
    int*   gcnt       = (int*)(bpl + 4096);
    float* feats_part = (float*)(gcnt + 10 * RSTRIDE);
    int2*  runlist    = (int2*)(feats_part + FROWS * 32);

    zero_kernel<<<2, 256, 0, stream>>>(gcnt);

    int nb_prep = 10 + (M + 512 + FROWS * 32 + 255) / 256;
    prep_kernel<<<nb_prep, 256, 0, stream>>>(
        conv_w, Wt, hf_w1, hs_w1, bph, bpl,
        idx_sorted, node_depth, gcnt, runlist, feats_part, M);

    int max_waves = (M + 3) / 4 + 10;
    conv_scan<<<(max_waves + 3) / 4, 256, 0, stream>>>(
        data, Wt, conv_b, depth_weight, idx_sorted, depth_sorted,
        gcnt, runlist, feats_part, patch, M);

    int nchunks = (L + 63) / 64;
    mlp_kernel<<<(nchunks + 3) / 4, 256, 0, stream>>>(
        data, feats_part, patch, leaf_idx, bph, bpl,
        hf_w1, hs_w1,
        hf_b1, hf_w2, hf_b2, hs_b1, hs_w2, hs_b2, out, L);
}

// Round 17
// 62.982 us; speedup vs baseline: 5.1559x; 5.1559x over previous
//
#include <hip/hip_runtime.h>
#include <hip/hip_bf16.h>
#include <math.h>

// ---------------------------------------------------------------------------
// M=30000 nodes, S=8 cells, D=32 channels, DEPTH_LIMIT=10, H=64, L=7M+1.
// 4 nodes: zero(gcnt) -> prep -> conv -> mlp.
// Round-17: conv blocks own 16 SAME-DEPTH runs; W[d] (32KB) staged into LDS
// with XOR swizzle (conflict-free ds_read_b128); all W reads hit LDS.
// Attribution (r16): conv was 23.5us, ~80% memory-latency stall on W loads.
// ---------------------------------------------------------------------------

typedef __attribute__((ext_vector_type(8))) short short8;
typedef __attribute__((ext_vector_type(4))) float f32x4;

#define WT_N 81920    // 10*32*32*8
#define RCAP 30720    // per-depth run-list capacity
#define RSTRIDE 32    // gcnt padding (ints): one counter per 128B line
#define FSLOTS 256    // feats_part rows (one 128B line each)

__device__ __forceinline__ unsigned short f2bf(float x) {
    __hip_bfloat16 h = __float2bfloat16(x);
    return *reinterpret_cast<unsigned short*>(&h);
}
__device__ __forceinline__ float bf2f(unsigned short h) {
    union { float f; unsigned u; } v; v.u = ((unsigned)h) << 16;
    return v.f;
}

__device__ __forceinline__ float4 shfl4(float4 v, int src) {
    float4 r;
    r.x = __shfl(v.x, src, 64);
    r.y = __shfl(v.y, src, 64);
    r.z = __shfl(v.z, src, 64);
    r.w = __shfl(v.w, src, 64);
    return r;
}

__device__ __forceinline__ void red_ig(float4& T) {
    #pragma unroll
    for (int m = 8; m <= 32; m <<= 1) {
        T.x += __shfl_xor(T.x, m, 64);
        T.y += __shfl_xor(T.y, m, 64);
        T.z += __shfl_xor(T.z, m, 64);
        T.w += __shfl_xor(T.w, m, 64);
    }
}

__device__ __forceinline__ float gelu_fast(float x)
{
    float e = __expf(-1.702f * x);
    return x * __builtin_amdgcn_rcpf(1.0f + e);
}

// Swizzled LDS W read: row = c*32 + i (i = ig*4+j), og8 = lane&7.
// float4 index g = row*8 + og8; bits 5-7 of g = ig -> XOR spreads the 8 ig
// lanes of an og8 group across all 8 bank groups (conflict-free b128).
__device__ __forceinline__ float4 ldsW4(const float4* tlW, int row, int og8) {
    int g = row * 8 + og8;
    return tlW[g ^ ((g >> 5) & 7)];
}

// Kernel Z: zero gcnt.
__global__ __launch_bounds__(256) void zero_kernel(int* __restrict__ dst)
{
    int i = blockIdx.x * 256 + threadIdx.x;
    if (i < 10 * RSTRIDE) dst[i] = 0;
}

// Kernel 0: blocks 0..9 -> LDS-tiled W transpose; blocks 10.. -> run detect +
// depth-bucketed scatter, w1 bf16 hi/lo pack, feats_part zero.
__global__ __launch_bounds__(256) void prep_kernel(
    const float* __restrict__ conv_w, float* __restrict__ Wt,
    const float* __restrict__ hf_w1, const float* __restrict__ hs_w1,
    short* __restrict__ bph, short* __restrict__ bpl,
    const int* __restrict__ idx_sorted, const int* __restrict__ node_depth,
    int* __restrict__ gcnt, int2* __restrict__ runlist,
    float* __restrict__ feats_part, int M)
{
    __shared__ float tl[32 * 257];
    __shared__ int hcnt[16], hbase[16];

    if (blockIdx.x < 10) {
        int d = blockIdx.x;
        int base = d * 8192;
        for (int t = threadIdx.x; t < 8192; t += 256)
            tl[(t >> 8) * 257 + (t & 255)] = conv_w[base + t];
        __syncthreads();
        for (int t = threadIdx.x; t < 8192; t += 256) {
            int o = t & 31, i = (t >> 5) & 31, k = t >> 10;
            Wt[base + t] = tl[o * 257 + i * 8 + k];
        }
        return;
    }

    if (threadIdx.x < 16) hcnt[threadIdx.x] = 0;
    __syncthreads();

    int j = (blockIdx.x - 10) * 256 + threadIdx.x;
    bool start = false;
    int d = 0, myp = 0, mypos = 0;

    if (j < M) {
        int p = idx_sorted[j] >> 3;
        start = (j == 0) || ((idx_sorted[j - 1] >> 3) != p);
        if (start) {
            d = node_depth[p];
            myp = p;
            mypos = atomicAdd(&hcnt[d], 1);
        }
    } else if (j < M + 512) {
        int jj = j - M;
        int lane = jj & 63;
        int q = jj >> 6;
        int m = q >> 2, tq = q & 3;
        int kg = lane >> 4, n0 = lane & 15, k0 = kg * 8;
        const float* __restrict__ w1 = m ? hs_w1 : hf_w1;
        #pragma unroll
        for (int i = 0; i < 8; ++i) {
            float w = w1[(k0 + i) * 64 + tq * 16 + n0];
            unsigned short hh = f2bf(w);
            bph[(q * 64 + lane) * 8 + i] = (short)hh;
            bpl[(q * 64 + lane) * 8 + i] = (short)f2bf(w - bf2f(hh));
        }
    } else if (j < M + 512 + FSLOTS * 32) {
        feats_part[j - (M + 512)] = 0.0f;
    }

    __syncthreads();
    if (threadIdx.x < 16) {
        int c = hcnt[threadIdx.x];
        if (c > 0) hbase[threadIdx.x] = atomicAdd(&gcnt[threadIdx.x * RSTRIDE], c);
    }
    __syncthreads();
    if (start) runlist[d * RCAP + hbase[d] + mypos] = make_int2(j, myp);
}

// Per-run sequential steps; W reads from swizzled LDS.
__device__ __forceinline__ void run_steps(
    float4& T, float4& blk, float4& pfs, int ec, float edw, int base16,
    int n, int p, bool valid, const float4* tlW, float4 bias,
    int og, int og8, int ig, float* __restrict__ patch)
{
    if (!valid) return;
    int c = __shfl(ec, base16, 64);
    float4 wc0 = ldsW4(tlW, c * 32 + ig * 4 + 0, og8);
    float4 wc1 = ldsW4(tlW, c * 32 + ig * 4 + 1, og8);
    float4 wc2 = ldsW4(tlW, c * 32 + ig * 4 + 2, og8);
    float4 wc3 = ldsW4(tlW, c * 32 + ig * 4 + 3, og8);

    for (int s = 0;; ++s) {
        float dw = __shfl(edw, base16 + s, 64);
        float4 feat = {T.x + bias.x, T.y + bias.y, T.z + bias.z, T.w + bias.w};
        pfs.x = fmaf(dw, feat.x, pfs.x); pfs.y = fmaf(dw, feat.y, pfs.y);
        pfs.z = fmaf(dw, feat.z, pfs.z); pfs.w = fmaf(dw, feat.w, pfs.w);

        if (s + 1 == n) {
            if (p == 0 && c == 0 && ig == 0)
                *(float4*)(patch + og) = feat;
            return;
        }

        int cn = __shfl(ec, base16 + s + 1, 64);
        float4 nw0 = ldsW4(tlW, cn * 32 + ig * 4 + 0, og8);
        float4 nw1 = ldsW4(tlW, cn * 32 + ig * 4 + 1, og8);
        float4 nw2 = ldsW4(tlW, cn * 32 + ig * 4 + 2, og8);
        float4 nw3 = ldsW4(tlW, cn * 32 + ig * 4 + 3, og8);

        float4 ov = shfl4(blk, c * 8 + og8);
        float4 du = {feat.x - ov.x, feat.y - ov.y, feat.z - ov.z, feat.w - ov.w};
        if (ig == c) blk = feat;                 // scatter write into tree
        float4 u = shfl4(du, og8 * 8 + ig);      // delta at chans ig*4..+3

        float4 a4;
        a4.x = u.x * wc0.x; a4.y = u.x * wc0.y;
        a4.z = u.x * wc0.z; a4.w = u.x * wc0.w;
        a4.x = fmaf(u.y, wc1.x, a4.x); a4.y = fmaf(u.y, wc1.y, a4.y);
        a4.z = fmaf(u.y, wc1.z, a4.z); a4.w = fmaf(u.y, wc1.w, a4.w);
        a4.x = fmaf(u.z, wc2.x, a4.x); a4.y = fmaf(u.z, wc2.y, a4.y);
        a4.z = fmaf(u.z, wc2.z, a4.z); a4.w = fmaf(u.z, wc2.w, a4.w);
        a4.x = fmaf(u.w, wc3.x, a4.x); a4.y = fmaf(u.w, wc3.y, a4.y);
        a4.z = fmaf(u.w, wc3.z, a4.z); a4.w = fmaf(u.w, wc3.w, a4.w);
        red_ig(a4);
        T.x += a4.x; T.y += a4.y; T.z += a4.z; T.w += a4.w;

        c = cn;
        wc0 = nw0; wc1 = nw1; wc2 = nw2; wc3 = nw3;
    }
}

#define FMA16(T, X) \
    T.x = fmaf(X.x, w0.x, T.x); T.y = fmaf(X.x, w0.y, T.y); \
    T.z = fmaf(X.x, w0.z, T.z); T.w = fmaf(X.x, w0.w, T.w); \
    T.x = fmaf(X.y, w1.x, T.x); T.y = fmaf(X.y, w1.y, T.y); \
    T.z = fmaf(X.y, w1.z, T.z); T.w = fmaf(X.y, w1.w, T.w); \
    T.x = fmaf(X.z, w2.x, T.x); T.y = fmaf(X.z, w2.y, T.y); \
    T.z = fmaf(X.z, w2.z, T.z); T.w = fmaf(X.z, w2.w, T.w); \
    T.x = fmaf(X.w, w3.x, T.x); T.y = fmaf(X.w, w3.y, T.y); \
    T.z = fmaf(X.w, w3.z, T.z); T.w = fmaf(X.w, w3.w, T.w);

// Kernel 1: one BLOCK per 16 same-depth runs (4 runs/wave). W[d] staged into
// swizzled LDS once per block; all matvec/step W reads are ds_read_b128.
__global__ __launch_bounds__(256, 4) void conv_scan(
    const float* __restrict__ data, const float* __restrict__ Wt,
    const float* __restrict__ conv_b, const float* __restrict__ depth_weight,
    const int* __restrict__ idx_sorted, const int* __restrict__ depth_sorted,
    const int* __restrict__ gcnt, const int2* __restrict__ runlist,
    float* __restrict__ feats_part, float* __restrict__ patch, int M)
{
    __shared__ __align__(16) float4 tlW[2048];   // swizzled W[d], 32KB
    __shared__ float fred[4][32];

    // block -> (bucket d, chunk of 16 runs): block-granular => uniform depth
    int acc = 0, d = -1, chunk = 0, cnt = 0;
    #pragma unroll
    for (int dd = 0; dd < 10; ++dd) {
        int c = gcnt[dd * RSTRIDE];
        int nb = (c + 15) >> 4;
        if (d < 0 && (int)blockIdx.x < acc + nb) {
            d = dd; chunk = (int)blockIdx.x - acc; cnt = c;
        }
        acc += nb;
    }
    if (d < 0) return;   // uniform across the block

    // cooperative swizzled stage of W[d] into LDS (coalesced global reads)
    {
        const float4* Wg = (const float4*)(Wt + d * 8192);
        for (int g = threadIdx.x; g < 2048; g += 256)
            tlW[g ^ ((g >> 5) & 7)] = Wg[g];
    }
    __syncthreads();

    int l = threadIdx.x & 63;
    int wv = threadIdx.x >> 6;
    int og8 = l & 7, og = og8 * 4, ig = l >> 3;
    int q = l >> 4;

    int r0 = chunk * 16 + wv * 4;
    float4 pfs = {0, 0, 0, 0};

    if (r0 < cnt) {                       // wave-uniform
        int rq = r0 + q; if (rq >= cnt) rq = cnt - 1;
        int2 e = runlist[d * RCAP + rq];
        int t0l = e.x, pl = e.y;

        int wl = l & 15;
        int tw = t0l + wl;
        int twc = tw < M ? tw : M - 1;
        int iw  = idx_sorted[twc];
        int dsw = depth_sorted[twc];
        unsigned long long mask = __ballot((tw < M) && ((iw >> 3) == pl));
        int   ec  = iw & 7;
        float edw = depth_weight[dsw & 15];

        const float4 bias = *(const float4*)(conv_b + d * 32 + og);

        int p0 = __shfl(pl, 0, 64),  p1 = __shfl(pl, 16, 64),
            p2 = __shfl(pl, 32, 64), p3 = __shfl(pl, 48, 64);
        int n0 = __builtin_ctz(~(unsigned)( mask        & 0xFFFFull));
        int n1 = __builtin_ctz(~(unsigned)((mask >> 16) & 0xFFFFull));
        int n2 = __builtin_ctz(~(unsigned)((mask >> 32) & 0xFFFFull));
        int n3 = __builtin_ctz(~(unsigned)((mask >> 48) & 0xFFFFull));
        bool v0 = (r0 + 0 < cnt), v1 = (r0 + 1 < cnt),
             v2 = (r0 + 2 < cnt), v3 = (r0 + 3 < cnt);

        float4 B0 = *(const float4*)(data + (size_t)p0 * 256 + ig * 32 + og);
        float4 B1 = *(const float4*)(data + (size_t)p1 * 256 + ig * 32 + og);
        float4 B2 = *(const float4*)(data + (size_t)p2 * 256 + ig * 32 + og);
        float4 B3 = *(const float4*)(data + (size_t)p3 * 256 + ig * 32 + og);

        float4 T0 = {0,0,0,0}, T1 = {0,0,0,0}, T2 = {0,0,0,0}, T3 = {0,0,0,0};
        #pragma unroll
        for (int k = 0; k < 8; ++k) {
            const float4 w0 = ldsW4(tlW, k * 32 + ig * 4 + 0, og8);
            const float4 w1 = ldsW4(tlW, k * 32 + ig * 4 + 1, og8);
            const float4 w2 = ldsW4(tlW, k * 32 + ig * 4 + 2, og8);
            const float4 w3 = ldsW4(tlW, k * 32 + ig * 4 + 3, og8);
            int src = k * 8 + ig;
            float4 x0 = shfl4(B0, src), x1 = shfl4(B1, src),
                   x2 = shfl4(B2, src), x3 = shfl4(B3, src);
            FMA16(T0, x0); FMA16(T1, x1); FMA16(T2, x2); FMA16(T3, x3);
        }
        red_ig(T0); red_ig(T1); red_ig(T2); red_ig(T3);

        run_steps(T0, B0, pfs, ec, edw,  0, n0, p0, v0, tlW, bias, og, og8, ig, patch);
        run_steps(T1, B1, pfs, ec, edw, 16, n1, p1, v1, tlW, bias, og, og8, ig, patch);
        run_steps(T2, B2, pfs, ec, edw, 32, n2, p2, v2, tlW, bias, og, og8, ig, patch);
        run_steps(T3, B3, pfs, ec, edw, 48, n3, p3, v3, tlW, bias, og, og8, ig, patch);
    }

    // block-level pf reduction -> 32 atomics per block onto FSLOTS rows
    if (ig == 0) {
        fred[wv][og + 0] = pfs.x;
        fred[wv][og + 1] = pfs.y;
        fred[wv][og + 2] = pfs.z;
        fred[wv][og + 3] = pfs.w;
    }
    __syncthreads();
    if (threadIdx.x < 32) {
        float s = fred[0][threadIdx.x] + fred[1][threadIdx.x]
                + fred[2][threadIdx.x] + fred[3][threadIdx.x];
        atomicAdd(&feats_part[(blockIdx.x & (FSLOTS - 1)) * 32 + threadIdx.x], s);
    }
}

// Kernel 2: leaf gather + both MLPs via MFMA (round-15 version).
__global__ __launch_bounds__(256, 4) void mlp_kernel(
    const float* __restrict__ data, const float* __restrict__ feats_part,
    const float* __restrict__ patch, const int* __restrict__ leaf_idx,
    const short* __restrict__ bph, const short* __restrict__ bpl,
    const float* __restrict__ hf_w1, const float* __restrict__ hs_w1,
    const float* __restrict__ hf_b1, const float* __restrict__ hf_w2,
    const float* __restrict__ hf_b2, const float* __restrict__ hs_b1,
    const float* __restrict__ hs_w2, const float* __restrict__ hs_b2,
    float* __restrict__ out, int L)
{
    __shared__ float red[256];
    __shared__ float sh_fts[32];
    __shared__ float sh_fvec[128];
    __shared__ __align__(16) short sh_b[4096];

    {
        int ch = threadIdx.x & 31, g = threadIdx.x >> 5;
        float s = 0.f;
        #pragma unroll
        for (int j = 0; j < FSLOTS / 8; ++j)
            s += feats_part[(g + j * 8) * 32 + ch];
        red[threadIdx.x] = s;
        __syncthreads();
        if (threadIdx.x < 128) red[threadIdx.x] += red[threadIdx.x + 128];
        __syncthreads();
        if (threadIdx.x < 64) red[threadIdx.x] += red[threadIdx.x + 64];
        __syncthreads();
        if (threadIdx.x < 32)
            sh_fts[threadIdx.x] = red[threadIdx.x] + red[threadIdx.x + 32];
        __syncthreads();
    }

    {
        const int4* src = (const int4*)bph;
        int4* dst = (int4*)sh_b;
        for (int t = threadIdx.x; t < 512; t += 256) dst[t] = src[t];

        if (threadIdx.x < 128) {
            int m = threadIdx.x >> 6, h = threadIdx.x & 63;
            const float* __restrict__ w1 = m ? hs_w1 : hf_w1;
            float s = 0.f;
            #pragma unroll
            for (int k = 0; k < 32; ++k) s = fmaf(sh_fts[k], w1[k * 64 + h], s);
            sh_fvec[threadIdx.x] = s;
        }
        __syncthreads();
    }

    int l = threadIdx.x & 63;
    int ck = blockIdx.x * 4 + (threadIdx.x >> 6);
    int nchunks = (L + 63) >> 6;
    if (ck >= nchunks) return;
    int base = ck * 64;
    int n0 = l & 15, kg = l >> 4, k0 = kg * 8;

    float w2r[16], b1r[8];
    #pragma unroll
    for (int t = 0; t < 4; ++t) {
        int h = t * 16 + n0;
        w2r[t * 4 + 0] = hf_w2[h * 3 + 0];
        w2r[t * 4 + 1] = hf_w2[h * 3 + 1];
        w2r[t * 4 + 2] = hf_w2[h * 3 + 2];
        w2r[t * 4 + 3] = hs_w2[h];
        b1r[t]     = hf_b1[h] + sh_fvec[h];
        b1r[4 + t] = hs_b1[h] + sh_fvec[64 + h];
    }
    float b20 = hf_b2[0], b21 = hf_b2[1], b22 = hf_b2[2], b23 = hs_b2[0];

    #pragma unroll
    for (int tm = 0; tm < 4; ++tm) {
        int r  = base + tm * 16 + n0;
        int rc = r < L ? r : L - 1;
        int row = leaf_idx[rc];
        const float* __restrict__ src = (row == 0) ? patch : (data + (size_t)row * 32);
        float4 vA = *(const float4*)(src + k0);
        float4 vB = *(const float4*)(src + k0 + 4);
        float xv[8] = {vA.x, vA.y, vA.z, vA.w, vB.x, vB.y, vB.z, vB.w};
        short8 ahi;
        #pragma unroll
        for (int i = 0; i < 8; ++i) ahi[i] = (short)f2bf(xv[i]);

        f32x4 acc[8];
        bool anyPatch = __any(row == 0);
        if (!anyPatch) {
            #pragma unroll
            for (int qq = 0; qq < 8; ++qq) {
                short8 bh = *(const short8*)(sh_b + (qq * 64 + l) * 8);
                float bv = b1r[qq];
                f32x4 a = (f32x4){bv, bv, bv, bv};
                acc[qq] = __builtin_amdgcn_mfma_f32_16x16x32_bf16(ahi, bh, a, 0, 0, 0);
            }
        } else {
            short8 alo;
            #pragma unroll
            for (int i = 0; i < 8; ++i) {
                unsigned short hh = (unsigned short)ahi[i];
                alo[i] = (short)f2bf(xv[i] - bf2f(hh));
            }
            #pragma unroll
            for (int qq = 0; qq < 8; ++qq) {
                short8 bh = *(const short8*)(sh_b + (qq * 64 + l) * 8);
                short8 bl = *(const short8*)(bpl + (qq * 64 + l) * 8);
                float bv = b1r[qq];
                f32x4 a = (f32x4){bv, bv, bv, bv};
                a = __builtin_amdgcn_mfma_f32_16x16x32_bf16(ahi, bh, a, 0, 0, 0);
                a = __builtin_amdgcn_mfma_f32_16x16x32_bf16(alo, bh, a, 0, 0, 0);
                a = __builtin_amdgcn_mfma_f32_16x16x32_bf16(ahi, bl, a, 0, 0, 0);
                acc[qq] = a;
            }
        }

        float o[4][4];
        #pragma unroll
        for (int g2 = 0; g2 < 4; ++g2) {
            #pragma unroll
            for (int c = 0; c < 4; ++c) o[g2][c] = 0.f;
        }
        #pragma unroll
        for (int t = 0; t < 4; ++t) {
            #pragma unroll
            for (int reg = 0; reg < 4; ++reg) {
                float gf = gelu_fast(acc[t][reg]);
                float gs = gelu_fast(acc[4 + t][reg]);
                o[reg][0] = fmaf(gf, w2r[t * 4 + 0], o[reg][0]);
                o[reg][1] = fmaf(gf, w2r[t * 4 + 1], o[reg][1]);
                o[reg][2] = fmaf(gf, w2r[t * 4 + 2], o[reg][2]);
                o[reg][3] = fmaf(gs, w2r[t * 4 + 3], o[reg][3]);
            }
        }
        #pragma unroll
        for (int mk = 1; mk < 16; mk <<= 1) {
            #pragma unroll
            for (int reg = 0; reg < 4; ++reg) {
                #pragma unroll
                for (int c = 0; c < 4; ++c)
                    o[reg][c] += __shfl_xor(o[reg][c], mk, 64);
            }
        }
        if (n0 < 4) {
            int rL = base + tm * 16 + kg * 4 + n0;
            if (rL < L) {
                float s0 = n0 == 0 ? o[0][0] : n0 == 1 ? o[1][0] : n0 == 2 ? o[2][0] : o[3][0];
                float s1 = n0 == 0 ? o[0][1] : n0 == 1 ? o[1][1] : n0 == 2 ? o[2][1] : o[3][1];
                float s2 = n0 == 0 ? o[0][2] : n0 == 1 ? o[1][2] : n0 == 2 ? o[2][2] : o[3][2];
                float s3 = n0 == 0 ? o[0][3] : n0 == 1 ? o[1][3] : n0 == 2 ? o[2][3] : o[3][3];
                float4 res = {s0 + b20, s1 + b21, s2 + b22, s3 + b23};
                *(float4*)(out + (size_t)rL * 4) = res;
            }
        }
    }
}

extern "C" void kernel_launch(void* const* d_in, const int* in_sizes, int n_in,
                              void* d_out, int out_size, void* d_ws, size_t ws_size,
                              hipStream_t stream)
{
    const float* data         = (const float*)d_in[0];
    const float* conv_w       = (const float*)d_in[1];
    const float* conv_b       = (const float*)d_in[2];
    const float* depth_weight = (const float*)d_in[3];
    const float* hf_w1        = (const float*)d_in[4];
    const float* hf_b1        = (const float*)d_in[5];
    const float* hf_w2        = (const float*)d_in[6];
    const float* hf_b2        = (const float*)d_in[7];
    const float* hs_w1        = (const float*)d_in[8];
    const float* hs_b1        = (const float*)d_in[9];
    const float* hs_w2        = (const float*)d_in[10];
    const float* hs_b2        = (const float*)d_in[11];
    const int*   idx_sorted   = (const int*)d_in[12];
    const int*   depth_sorted = (const int*)d_in[13];
    const int*   node_depth   = (const int*)d_in[14];
    const int*   leaf_idx     = (const int*)d_in[15];

    int M = in_sizes[12];   // 30000
    int L = in_sizes[15];   // 210001
    float* out = (float*)d_out;

    float* Wt         = (float*)d_ws;
    float* patch      = Wt + WT_N;
    short* bph        = (short*)(patch + 32);
    short* bpl        = bph + 4096;
    int*   gcnt       = (int*)(bpl + 4096);
    float* feats_part = (float*)(gcnt + 10 * RSTRIDE);
    int2*  runlist    = (int2*)(feats_part + FSLOTS * 32);

    zero_kernel<<<2, 256, 0, stream>>>(gcnt);

    int nb_prep = 10 + (M + 512 + FSLOTS * 32 + 255) / 256;
    prep_kernel<<<nb_prep, 256, 0, stream>>>(
        conv_w, Wt, hf_w1, hs_w1, bph, bpl,
        idx_sorted, node_depth, gcnt, runlist, feats_part, M);

    // blocks: each covers 16 same-depth runs; <=10 buckets of padding
    int nb_conv = (M + 15) / 16 + 10;
    conv_scan<<<nb_conv, 256, 0, stream>>>(
        data, Wt, conv_b, depth_weight, idx_sorted, depth_sorted,
        gcnt, runlist, feats_part, patch, M);

    int nchunks = (L + 63) / 64;
    mlp_kernel<<<(nchunks + 3) / 4, 256, 0, stream>>>(
        data, feats_part, patch, leaf_idx, bph, bpl,
        hf_w1, hs_w1,
        hf_b1, hf_w2, hf_b2, hs_b1, hs_w2, hs_b2, out, L);
}

// Round 18
// 57.764 us; speedup vs baseline: 5.6216x; 1.0903x over previous
//
#include <hip/hip_runtime.h>
#include <hip/hip_bf16.h>
#include <math.h>

// ---------------------------------------------------------------------------
// M=30000 nodes, S=8 cells, D=32 channels, DEPTH_LIMIT=10, H=64, L=7M+1.
// 4 nodes: zero(gcnt) -> prep -> conv(4-run batched) -> mlp.
// Round-18: conv matvec x-broadcasts (128 shfl4 DS ops/wave) replaced by
// direct global column loads (L1-broadcast) — conv is DS-throughput-bound
// (r16 attribution: 300 DS/wave * 5.8cyc / 256 CU ~= 21us of 23.5us).
// ---------------------------------------------------------------------------

typedef __attribute__((ext_vector_type(8))) short short8;
typedef __attribute__((ext_vector_type(4))) float f32x4;

#define WT_N 81920    // 10*32*32*8
#define RCAP 30720    // per-depth run-list capacity
#define RSTRIDE 32    // gcnt padding (ints): one counter per 128B line
#define FSLOTS 256    // feats_part rows (one 128B line each)

__device__ __forceinline__ unsigned short f2bf(float x) {
    __hip_bfloat16 h = __float2bfloat16(x);
    return *reinterpret_cast<unsigned short*>(&h);
}
__device__ __forceinline__ float bf2f(unsigned short h) {
    union { float f; unsigned u; } v; v.u = ((unsigned)h) << 16;
    return v.f;
}

__device__ __forceinline__ float4 shfl4(float4 v, int src) {
    float4 r;
    r.x = __shfl(v.x, src, 64);
    r.y = __shfl(v.y, src, 64);
    r.z = __shfl(v.z, src, 64);
    r.w = __shfl(v.w, src, 64);
    return r;
}

__device__ __forceinline__ void red_ig(float4& T) {
    #pragma unroll
    for (int m = 8; m <= 32; m <<= 1) {
        T.x += __shfl_xor(T.x, m, 64);
        T.y += __shfl_xor(T.y, m, 64);
        T.z += __shfl_xor(T.z, m, 64);
        T.w += __shfl_xor(T.w, m, 64);
    }
}

__device__ __forceinline__ float gelu_fast(float x)
{
    float e = __expf(-1.702f * x);
    return x * __builtin_amdgcn_rcpf(1.0f + e);
}

// Kernel Z: zero gcnt.
__global__ __launch_bounds__(256) void zero_kernel(int* __restrict__ dst)
{
    int i = blockIdx.x * 256 + threadIdx.x;
    if (i < 10 * RSTRIDE) dst[i] = 0;
}

// Kernel 0: blocks 0..9 -> LDS-tiled W transpose; blocks 10.. -> run detect +
// depth-bucketed scatter, w1 bf16 hi/lo pack, feats_part zero.
__global__ __launch_bounds__(256) void prep_kernel(
    const float* __restrict__ conv_w, float* __restrict__ Wt,
    const float* __restrict__ hf_w1, const float* __restrict__ hs_w1,
    short* __restrict__ bph, short* __restrict__ bpl,
    const int* __restrict__ idx_sorted, const int* __restrict__ node_depth,
    int* __restrict__ gcnt, int2* __restrict__ runlist,
    float* __restrict__ feats_part, int M)
{
    __shared__ float tl[32 * 257];
    __shared__ int hcnt[16], hbase[16];

    if (blockIdx.x < 10) {
        int d = blockIdx.x;
        int base = d * 8192;
        for (int t = threadIdx.x; t < 8192; t += 256)
            tl[(t >> 8) * 257 + (t & 255)] = conv_w[base + t];
        __syncthreads();
        for (int t = threadIdx.x; t < 8192; t += 256) {
            int o = t & 31, i = (t >> 5) & 31, k = t >> 10;
            Wt[base + t] = tl[o * 257 + i * 8 + k];
        }
        return;
    }

    if (threadIdx.x < 16) hcnt[threadIdx.x] = 0;
    __syncthreads();

    int j = (blockIdx.x - 10) * 256 + threadIdx.x;
    bool start = false;
    int d = 0, myp = 0, mypos = 0;

    if (j < M) {
        int p = idx_sorted[j] >> 3;
        start = (j == 0) || ((idx_sorted[j - 1] >> 3) != p);
        if (start) {
            d = node_depth[p];
            myp = p;
            mypos = atomicAdd(&hcnt[d], 1);
        }
    } else if (j < M + 512) {
        int jj = j - M;
        int lane = jj & 63;
        int q = jj >> 6;
        int m = q >> 2, tq = q & 3;
        int kg = lane >> 4, n0 = lane & 15, k0 = kg * 8;
        const float* __restrict__ w1 = m ? hs_w1 : hf_w1;
        #pragma unroll
        for (int i = 0; i < 8; ++i) {
            float w = w1[(k0 + i) * 64 + tq * 16 + n0];
            unsigned short hh = f2bf(w);
            bph[(q * 64 + lane) * 8 + i] = (short)hh;
            bpl[(q * 64 + lane) * 8 + i] = (short)f2bf(w - bf2f(hh));
        }
    } else if (j < M + 512 + FSLOTS * 32) {
        feats_part[j - (M + 512)] = 0.0f;
    }

    __syncthreads();
    if (threadIdx.x < 16) {
        int c = hcnt[threadIdx.x];
        if (c > 0) hbase[threadIdx.x] = atomicAdd(&gcnt[threadIdx.x * RSTRIDE], c);
    }
    __syncthreads();
    if (start) runlist[d * RCAP + hbase[d] + mypos] = make_int2(j, myp);
}

// Per-run sequential steps (inline; valid/n/p/base16 are wave-uniform).
__device__ __forceinline__ void run_steps(
    float4& T, float4& blk, float4& pfs, int ec, float edw, int base16,
    int n, int p, bool valid, const float* __restrict__ W, float4 bias,
    int og, int og8, int ig, float* __restrict__ patch)
{
    if (!valid) return;
    int c = __shfl(ec, base16, 64);
    float4 wc0 = *(const float4*)(W + (c * 32 + ig * 4 + 0) * 32 + og);
    float4 wc1 = *(const float4*)(W + (c * 32 + ig * 4 + 1) * 32 + og);
    float4 wc2 = *(const float4*)(W + (c * 32 + ig * 4 + 2) * 32 + og);
    float4 wc3 = *(const float4*)(W + (c * 32 + ig * 4 + 3) * 32 + og);

    for (int s = 0;; ++s) {
        float dw = __shfl(edw, base16 + s, 64);
        float4 feat = {T.x + bias.x, T.y + bias.y, T.z + bias.z, T.w + bias.w};
        pfs.x = fmaf(dw, feat.x, pfs.x); pfs.y = fmaf(dw, feat.y, pfs.y);
        pfs.z = fmaf(dw, feat.z, pfs.z); pfs.w = fmaf(dw, feat.w, pfs.w);

        if (s + 1 == n) {
            if (p == 0 && c == 0 && ig == 0)
                *(float4*)(patch + og) = feat;
            return;
        }

        int cn = __shfl(ec, base16 + s + 1, 64);
        float4 nw0 = *(const float4*)(W + (cn * 32 + ig * 4 + 0) * 32 + og);
        float4 nw1 = *(const float4*)(W + (cn * 32 + ig * 4 + 1) * 32 + og);
        float4 nw2 = *(const float4*)(W + (cn * 32 + ig * 4 + 2) * 32 + og);
        float4 nw3 = *(const float4*)(W + (cn * 32 + ig * 4 + 3) * 32 + og);

        float4 ov = shfl4(blk, c * 8 + og8);
        float4 du = {feat.x - ov.x, feat.y - ov.y, feat.z - ov.z, feat.w - ov.w};
        if (ig == c) blk = feat;                 // scatter write into tree
        float4 u = shfl4(du, og8 * 8 + ig);      // delta at chans ig*4..+3

        float4 a4;
        a4.x = u.x * wc0.x; a4.y = u.x * wc0.y;
        a4.z = u.x * wc0.z; a4.w = u.x * wc0.w;
        a4.x = fmaf(u.y, wc1.x, a4.x); a4.y = fmaf(u.y, wc1.y, a4.y);
        a4.z = fmaf(u.y, wc1.z, a4.z); a4.w = fmaf(u.y, wc1.w, a4.w);
        a4.x = fmaf(u.z, wc2.x, a4.x); a4.y = fmaf(u.z, wc2.y, a4.y);
        a4.z = fmaf(u.z, wc2.z, a4.z); a4.w = fmaf(u.z, wc2.w, a4.w);
        a4.x = fmaf(u.w, wc3.x, a4.x); a4.y = fmaf(u.w, wc3.y, a4.y);
        a4.z = fmaf(u.w, wc3.z, a4.z); a4.w = fmaf(u.w, wc3.w, a4.w);
        red_ig(a4);
        T.x += a4.x; T.y += a4.y; T.z += a4.z; T.w += a4.w;

        c = cn;
        wc0 = nw0; wc1 = nw1; wc2 = nw2; wc3 = nw3;
    }
}

#define FMA16(T, X) \
    T.x = fmaf(X.x, w0.x, T.x); T.y = fmaf(X.x, w0.y, T.y); \
    T.z = fmaf(X.x, w0.z, T.z); T.w = fmaf(X.x, w0.w, T.w); \
    T.x = fmaf(X.y, w1.x, T.x); T.y = fmaf(X.y, w1.y, T.y); \
    T.z = fmaf(X.y, w1.z, T.z); T.w = fmaf(X.y, w1.w, T.w); \
    T.x = fmaf(X.z, w2.x, T.x); T.y = fmaf(X.z, w2.y, T.y); \
    T.z = fmaf(X.z, w2.z, T.z); T.w = fmaf(X.z, w2.w, T.w); \
    T.x = fmaf(X.w, w3.x, T.x); T.y = fmaf(X.w, w3.y, T.y); \
    T.z = fmaf(X.w, w3.z, T.z); T.w = fmaf(X.w, w3.w, T.w);

// Kernel 1: one wave per 4 SAME-DEPTH runs. Matvec x values loaded DIRECTLY
// from global (contiguous 128B per (run,k) -> L1 line broadcast) instead of
// shfl4 cross-lane broadcasts: -128 DS ops/wave on the DS-bound pipe.
__global__ __launch_bounds__(256, 4) void conv_scan(
    const float* __restrict__ data, const float* __restrict__ Wt,
    const float* __restrict__ conv_b, const float* __restrict__ depth_weight,
    const int* __restrict__ idx_sorted, const int* __restrict__ depth_sorted,
    const int* __restrict__ gcnt, const int2* __restrict__ runlist,
    float* __restrict__ feats_part, float* __restrict__ patch, int M)
{
    __shared__ float fred[4][32];

    int w = (blockIdx.x * 256 + threadIdx.x) >> 6;
    int l = threadIdx.x & 63;
    int wv = threadIdx.x >> 6;
    int og8 = l & 7, og = og8 * 4, ig = l >> 3;
    int q = l >> 4;

    int acc = 0, d = -1, chunk = 0, cnt = 0;
    #pragma unroll
    for (int dd = 0; dd < 10; ++dd) {
        int c = gcnt[dd * RSTRIDE];
        int nw = (c + 3) >> 2;
        if (d < 0 && w < acc + nw) { d = dd; chunk = w - acc; cnt = c; }
        acc += nw;
    }

    float4 pfs = {0, 0, 0, 0};
    if (d >= 0) {
        int r0 = chunk * 4;
        int rq = r0 + q; if (rq >= cnt) rq = cnt - 1;
        int2 e = runlist[d * RCAP + rq];
        int t0l = e.x, pl = e.y;

        int wl = l & 15;
        int tw = t0l + wl;
        int twc = tw < M ? tw : M - 1;
        int iw  = idx_sorted[twc];
        int dsw = depth_sorted[twc];
        unsigned long long mask = __ballot((tw < M) && ((iw >> 3) == pl));
        int   ec  = iw & 7;
        float edw = depth_weight[dsw & 15];

        const float* __restrict__ W = Wt + d * 8192;    // [k][i][o]
        const float4 bias = *(const float4*)(conv_b + d * 32 + og);

        int p0 = __shfl(pl, 0, 64),  p1 = __shfl(pl, 16, 64),
            p2 = __shfl(pl, 32, 64), p3 = __shfl(pl, 48, 64);
        int n0 = __builtin_ctz(~(unsigned)( mask        & 0xFFFFull));
        int n1 = __builtin_ctz(~(unsigned)((mask >> 16) & 0xFFFFull));
        int n2 = __builtin_ctz(~(unsigned)((mask >> 32) & 0xFFFFull));
        int n3 = __builtin_ctz(~(unsigned)((mask >> 48) & 0xFFFFull));
        bool v0 = (r0 + 0 < cnt), v1 = (r0 + 1 < cnt),
             v2 = (r0 + 2 < cnt), v3 = (r0 + 3 < cnt);

        // block rows for the step phase (one float4/lane per run)
        float4 B0 = *(const float4*)(data + (size_t)p0 * 256 + ig * 32 + og);
        float4 B1 = *(const float4*)(data + (size_t)p1 * 256 + ig * 32 + og);
        float4 B2 = *(const float4*)(data + (size_t)p2 * 256 + ig * 32 + og);
        float4 B3 = *(const float4*)(data + (size_t)p3 * 256 + ig * 32 + og);

        // batched full matvec; x loaded directly (no cross-lane broadcast)
        float4 T0 = {0,0,0,0}, T1 = {0,0,0,0}, T2 = {0,0,0,0}, T3 = {0,0,0,0};
        #pragma unroll
        for (int k = 0; k < 8; ++k) {
            const float4 w0 = *(const float4*)(W + (k * 32 + ig * 4 + 0) * 32 + og);
            const float4 w1 = *(const float4*)(W + (k * 32 + ig * 4 + 1) * 32 + og);
            const float4 w2 = *(const float4*)(W + (k * 32 + ig * 4 + 2) * 32 + og);
            const float4 w3 = *(const float4*)(W + (k * 32 + ig * 4 + 3) * 32 + og);
            float4 x0 = *(const float4*)(data + (size_t)p0 * 256 + k * 32 + ig * 4);
            float4 x1 = *(const float4*)(data + (size_t)p1 * 256 + k * 32 + ig * 4);
            float4 x2 = *(const float4*)(data + (size_t)p2 * 256 + k * 32 + ig * 4);
            float4 x3 = *(const float4*)(data + (size_t)p3 * 256 + k * 32 + ig * 4);
            FMA16(T0, x0); FMA16(T1, x1); FMA16(T2, x2); FMA16(T3, x3);
        }
        red_ig(T0); red_ig(T1); red_ig(T2); red_ig(T3);

        run_steps(T0, B0, pfs, ec, edw,  0, n0, p0, v0, W, bias, og, og8, ig, patch);
        run_steps(T1, B1, pfs, ec, edw, 16, n1, p1, v1, W, bias, og, og8, ig, patch);
        run_steps(T2, B2, pfs, ec, edw, 32, n2, p2, v2, W, bias, og, og8, ig, patch);
        run_steps(T3, B3, pfs, ec, edw, 48, n3, p3, v3, W, bias, og, og8, ig, patch);
    }

    // block-level pf reduction -> 32 atomics per block onto FSLOTS rows
    if (ig == 0) {
        fred[wv][og + 0] = pfs.x;
        fred[wv][og + 1] = pfs.y;
        fred[wv][og + 2] = pfs.z;
        fred[wv][og + 3] = pfs.w;
    }
    __syncthreads();
    if (threadIdx.x < 32) {
        float s = fred[0][threadIdx.x] + fred[1][threadIdx.x]
                + fred[2][threadIdx.x] + fred[3][threadIdx.x];
        atomicAdd(&feats_part[(blockIdx.x & (FSLOTS - 1)) * 32 + threadIdx.x], s);
    }
}

// Kernel 2: leaf gather + both MLPs via MFMA (round-15 version).
__global__ __launch_bounds__(256, 4) void mlp_kernel(
    const float* __restrict__ data, const float* __restrict__ feats_part,
    const float* __restrict__ patch, const int* __restrict__ leaf_idx,
    const short* __restrict__ bph, const short* __restrict__ bpl,
    const float* __restrict__ hf_w1, const float* __restrict__ hs_w1,
    const float* __restrict__ hf_b1, const float* __restrict__ hf_w2,
    const float* __restrict__ hf_b2, const float* __restrict__ hs_b1,
    const float* __restrict__ hs_w2, const float* __restrict__ hs_b2,
    float* __restrict__ out, int L)
{
    __shared__ float red[256];
    __shared__ float sh_fts[32];
    __shared__ float sh_fvec[128];
    __shared__ __align__(16) short sh_b[4096];

    {
        int ch = threadIdx.x & 31, g = threadIdx.x >> 5;
        float s = 0.f;
        #pragma unroll
        for (int j = 0; j < FSLOTS / 8; ++j)
            s += feats_part[(g + j * 8) * 32 + ch];
        red[threadIdx.x] = s;
        __syncthreads();
        if (threadIdx.x < 128) red[threadIdx.x] += red[threadIdx.x + 128];
        __syncthreads();
        if (threadIdx.x < 64) red[threadIdx.x] += red[threadIdx.x + 64];
        __syncthreads();
        if (threadIdx.x < 32)
            sh_fts[threadIdx.x] = red[threadIdx.x] + red[threadIdx.x + 32];
        __syncthreads();
    }

    {
        const int4* src = (const int4*)bph;
        int4* dst = (int4*)sh_b;
        for (int t = threadIdx.x; t < 512; t += 256) dst[t] = src[t];

        if (threadIdx.x < 128) {
            int m = threadIdx.x >> 6, h = threadIdx.x & 63;
            const float* __restrict__ w1 = m ? hs_w1 : hf_w1;
            float s = 0.f;
            #pragma unroll
            for (int k = 0; k < 32; ++k) s = fmaf(sh_fts[k], w1[k * 64 + h], s);
            sh_fvec[threadIdx.x] = s;
        }
        __syncthreads();
    }

    int l = threadIdx.x & 63;
    int ck = blockIdx.x * 4 + (threadIdx.x >> 6);
    int nchunks = (L + 63) >> 6;
    if (ck >= nchunks) return;
    int base = ck * 64;
    int n0 = l & 15, kg = l >> 4, k0 = kg * 8;

    float w2r[16], b1r[8];
    #pragma unroll
    for (int t = 0; t < 4; ++t) {
        int h = t * 16 + n0;
        w2r[t * 4 + 0] = hf_w2[h * 3 + 0];
        w2r[t * 4 + 1] = hf_w2[h * 3 + 1];
        w2r[t * 4 + 2] = hf_w2[h * 3 + 2];
        w2r[t * 4 + 3] = hs_w2[h];
        b1r[t]     = hf_b1[h] + sh_fvec[h];
        b1r[4 + t] = hs_b1[h] + sh_fvec[64 + h];
    }
    float b20 = hf_b2[0], b21 = hf_b2[1], b22 = hf_b2[2], b23 = hs_b2[0];

    #pragma unroll
    for (int tm = 0; tm < 4; ++tm) {
        int r  = base + tm * 16 + n0;
        int rc = r < L ? r : L - 1;
        int row = leaf_idx[rc];
        const float* __restrict__ src = (row == 0) ? patch : (data + (size_t)row * 32);
        float4 vA = *(const float4*)(src + k0);
        float4 vB = *(const float4*)(src + k0 + 4);
        float xv[8] = {vA.x, vA.y, vA.z, vA.w, vB.x, vB.y, vB.z, vB.w};
        short8 ahi;
        #pragma unroll
        for (int i = 0; i < 8; ++i) ahi[i] = (short)f2bf(xv[i]);

        f32x4 acc[8];
        bool anyPatch = __any(row == 0);
        if (!anyPatch) {
            #pragma unroll
            for (int qq = 0; qq < 8; ++qq) {
                short8 bh = *(const short8*)(sh_b + (qq * 64 + l) * 8);
                float bv = b1r[qq];
                f32x4 a = (f32x4){bv, bv, bv, bv};
                acc[qq] = __builtin_amdgcn_mfma_f32_16x16x32_bf16(ahi, bh, a, 0, 0, 0);
            }
        } else {
            short8 alo;
            #pragma unroll
            for (int i = 0; i < 8; ++i) {
                unsigned short hh = (unsigned short)ahi[i];
                alo[i] = (short)f2bf(xv[i] - bf2f(hh));
            }
            #pragma unroll
            for (int qq = 0; qq < 8; ++qq) {
                short8 bh = *(const short8*)(sh_b + (qq * 64 + l) * 8);
                short8 bl = *(const short8*)(bpl + (qq * 64 + l) * 8);
                float bv = b1r[qq];
                f32x4 a = (f32x4){bv, bv, bv, bv};
                a = __builtin_amdgcn_mfma_f32_16x16x32_bf16(ahi, bh, a, 0, 0, 0);
                a = __builtin_amdgcn_mfma_f32_16x16x32_bf16(alo, bh, a, 0, 0, 0);
                a = __builtin_amdgcn_mfma_f32_16x16x32_bf16(ahi, bl, a, 0, 0, 0);
                acc[qq] = a;
            }
        }

        float o[4][4];
        #pragma unroll
        for (int g2 = 0; g2 < 4; ++g2) {
            #pragma unroll
            for (int c = 0; c < 4; ++c) o[g2][c] = 0.f;
        }
        #pragma unroll
        for (int t = 0; t < 4; ++t) {
            #pragma unroll
            for (int reg = 0; reg < 4; ++reg) {
                float gf = gelu_fast(acc[t][reg]);
                float gs = gelu_fast(acc[4 + t][reg]);
                o[reg][0] = fmaf(gf, w2r[t * 4 + 0], o[reg][0]);
                o[reg][1] = fmaf(gf, w2r[t * 4 + 1], o[reg][1]);
                o[reg][2] = fmaf(gf, w2r[t * 4 + 2], o[reg][2]);
                o[reg][3] = fmaf(gs, w2r[t * 4 + 3], o[reg][3]);
            }
        }
        #pragma unroll
        for (int mk = 1; mk < 16; mk <<= 1) {
            #pragma unroll
            for (int reg = 0; reg < 4; ++reg) {
                #pragma unroll
                for (int c = 0; c < 4; ++c)
                    o[reg][c] += __shfl_xor(o[reg][c], mk, 64);
            }
        }
        if (n0 < 4) {
            int rL = base + tm * 16 + kg * 4 + n0;
            if (rL < L) {
                float s0 = n0 == 0 ? o[0][0] : n0 == 1 ? o[1][0] : n0 == 2 ? o[2][0] : o[3][0];
                float s1 = n0 == 0 ? o[0][1] : n0 == 1 ? o[1][1] : n0 == 2 ? o[2][1] : o[3][1];
                float s2 = n0 == 0 ? o[0][2] : n0 == 1 ? o[1][2] : n0 == 2 ? o[2][2] : o[3][2];
                float s3 = n0 == 0 ? o[0][3] : n0 == 1 ? o[1][3] : n0 == 2 ? o[2][3] : o[3][3];
                float4 res = {s0 + b20, s1 + b21, s2 + b22, s3 + b23};
                *(float4*)(out + (size_t)rL * 4) = res;
            }
        }
    }
}

extern "C" void kernel_launch(void* const* d_in, const int* in_sizes, int n_in,
                              void* d_out, int out_size, void* d_ws, size_t ws_size,
                              hipStream_t stream)
{
    const float* data         = (const float*)d_in[0];
    const float* conv_w       = (const float*)d_in[1];
    const float* conv_b       = (const float*)d_in[2];
    const float* depth_weight = (const float*)d_in[3];
    const float* hf_w1        = (const float*)d_in[4];
    const float* hf_b1        = (const float*)d_in[5];
    const float* hf_w2        = (const float*)d_in[6];
    const float* hf_b2        = (const float*)d_in[7];
    const float* hs_w1        = (const float*)d_in[8];
    const float* hs_b1        = (const float*)d_in[9];
    const float* hs_w2        = (const float*)d_in[10];
    const float* hs_b2        = (const float*)d_in[11];
    const int*   idx_sorted   = (const int*)d_in[12];
    const int*   depth_sorted = (const int*)d_in[13];
    const int*   node_depth   = (const int*)d_in[14];
    const int*   leaf_idx     = (const int*)d_in[15];

    int M = in_sizes[12];   // 30000
    int L = in_sizes[15];   // 210001
    float* out = (float*)d_out;

    float* Wt         = (float*)d_ws;
    float* patch      = Wt + WT_N;
    short* bph        = (short*)(patch + 32);
    short* bpl        = bph + 4096;
    int*   gcnt       = (int*)(bpl + 4096);
    float* feats_part = (float*)(gcnt + 10 * RSTRIDE);
    int2*  runlist    = (int2*)(feats_part + FSLOTS * 32);

    zero_kernel<<<2, 256, 0, stream>>>(gcnt);

    int nb_prep = 10 + (M + 512 + FSLOTS * 32 + 255) / 256;
    prep_kernel<<<nb_prep, 256, 0, stream>>>(
        conv_w, Wt, hf_w1, hs_w1, bph, bpl,
        idx_sorted, node_depth, gcnt, runlist, feats_part, M);

    int max_waves = (M + 3) / 4 + 10;
    conv_scan<<<(max_waves + 3) / 4, 256, 0, stream>>>(
        data, Wt, conv_b, depth_weight, idx_sorted, depth_sorted,
        gcnt, runlist, feats_part, patch, M);

    int nchunks = (L + 63) / 64;
    mlp_kernel<<<(nchunks + 3) / 4, 256, 0, stream>>>(
        data, feats_part, patch, leaf_idx, bph, bpl,
        hf_w1, hs_w1,
        hf_b1, hf_w2, hf_b2, hs_b1, hs_w2, hs_b2, out, L);
}